// Round 3
// baseline (312.297 us; speedup 1.0000x reference)
//
#include <hip/hip_runtime.h>
#include <math.h>

// Problem constants (fixed by setup_inputs)
#define Nn 4
#define Ll 4096
#define Ss 256
#define Cc 256
#define Hh 256
#define FC 8
#define SC 32

// ---------------------------------------------------------------------------
// Tiled fp32 GEMM: C[M][ldc] = A[M][256] @ W[N][256]^T + bias, tile 128x64.
// Block 128 threads, per-thread 8 rows x 8 cols.
// LDS swizzle: word (r,k) stored at r*32 + (k ^ 4*(((r>>3)^r)&7)).
// Reads: A-address varies only with tr (8 distinct/wave, conflict-free after
// swizzle); B with tc (8 distinct, conflict-free). Staging writes also
// conflict-free (swizzle varies per row within each instruction).
// LDS-pipe floor: 16 b128 / 256 fma = 1.0 B/fma-lane -> ~20.5us per 2.15GF.
// ---------------------------------------------------------------------------
__global__ __launch_bounds__(128) void gemm_k(
    const float* __restrict__ A, const float* __restrict__ W,
    const float* __restrict__ bias, float* __restrict__ C, int ldc) {
  __shared__ float As[128 * 32];  // 16 KB
  __shared__ float Bs[64 * 32];   //  8 KB
  int t = threadIdx.x;
  int tc = t & 7, tr = t >> 3;    // 8 thread-cols x 16 thread-rows
  size_t row0 = (size_t)blockIdx.x * 128;
  int cb0 = blockIdx.y * 64;

  float acc[8][8];
  float4 bb0 = *(const float4*)&bias[cb0 + 8 * tc];
  float4 bb1 = *(const float4*)&bias[cb0 + 8 * tc + 4];
#pragma unroll
  for (int i = 0; i < 8; i++) {
    acc[i][0] = bb0.x; acc[i][1] = bb0.y; acc[i][2] = bb0.z; acc[i][3] = bb0.w;
    acc[i][4] = bb1.x; acc[i][5] = bb1.y; acc[i][6] = bb1.z; acc[i][7] = bb1.w;
  }

  for (int kt = 0; kt < 8; kt++) {
    if (kt) __syncthreads();
    // stage A tile 128x32 (8 float4 per thread)
#pragma unroll
    for (int it = 0; it < 8; it++) {
      int i2 = t + 128 * it;
      int r = i2 >> 3, j = i2 & 7;
      float4 v = *(const float4*)(A + (row0 + r) * Cc + kt * 32 + 4 * j);
      *(float4*)&As[r * 32 + ((4 * j) ^ ((((r >> 3) ^ r) & 7) << 2))] = v;
    }
    // stage B tile 64x32 (4 float4 per thread)
#pragma unroll
    for (int it = 0; it < 4; it++) {
      int i2 = t + 128 * it;
      int c = i2 >> 3, j = i2 & 7;
      float4 v = *(const float4*)(W + (size_t)(cb0 + c) * Cc + kt * 32 + 4 * j);
      *(float4*)&Bs[c * 32 + ((4 * j) ^ ((((c >> 3) ^ c) & 7) << 2))] = v;
    }
    __syncthreads();

#pragma unroll
    for (int kq = 0; kq < 8; kq++) {
      float4 Bv[8];
#pragma unroll
      for (int c = 0; c < 8; c++)
        Bv[c] = *(const float4*)&Bs[(8 * tc + c) * 32 +
                                    ((4 * kq) ^ (((tc ^ c) & 7) << 2))];
#pragma unroll
      for (int i = 0; i < 8; i++) {
        float4 Av = *(const float4*)&As[(8 * tr + i) * 32 +
                                        ((4 * kq) ^ (((tr ^ i) & 7) << 2))];
#pragma unroll
        for (int c = 0; c < 8; c++) {
          acc[i][c] = fmaf(Av.x, Bv[c].x, acc[i][c]);
          acc[i][c] = fmaf(Av.y, Bv[c].y, acc[i][c]);
          acc[i][c] = fmaf(Av.z, Bv[c].z, acc[i][c]);
          acc[i][c] = fmaf(Av.w, Bv[c].w, acc[i][c]);
        }
      }
    }
  }

#pragma unroll
  for (int i = 0; i < 8; i++) {
    float4 o0, o1;
    o0.x = acc[i][0]; o0.y = acc[i][1]; o0.z = acc[i][2]; o0.w = acc[i][3];
    o1.x = acc[i][4]; o1.y = acc[i][5]; o1.z = acc[i][6]; o1.w = acc[i][7];
    float* cr = C + (row0 + 8 * tr + i) * (size_t)ldc + cb0 + 8 * tc;
    *(float4*)cr = o0;
    *(float4*)(cr + 4) = o1;
  }
}

// ---------------------------------------------------------------------------
// Split c1t[1024][512] -> cpn[n][f][s][32] (l2-normalized point) and
// cval[n][f][s][32]. 32 lanes per (row,f) group; shfl-reduce the sumsq.
// ---------------------------------------------------------------------------
__global__ __launch_bounds__(256) void split_k(
    const float* __restrict__ c1t, float* __restrict__ cpn,
    float* __restrict__ cval) {
  int t = threadIdx.x;
  int g = blockIdx.x * 8 + (t >> 5);  // 8192 groups = 1024 rows x 8 fibers
  int j = t & 31;
  int f = g & 7;
  int row = g >> 3;  // n*256 + s
  const float* base = c1t + (size_t)row * 512 + f * 64;
  float p = base[j], v = base[32 + j];
  float ss = p * p;
#pragma unroll
  for (int m = 1; m <= 16; m <<= 1) ss += __shfl_xor(ss, m, 64);
  float rin = 1.f / fmaxf(sqrtf(ss), 1e-12f);
  int nI = row >> 8, s = row & 255;
  size_t ob = (((size_t)nI * FC + f) * Ss + s) * SC + j;
  cpn[ob] = p * rin;
  cval[ob] = v;
}

// ---------------------------------------------------------------------------
// sim as batched GEMM: per block one (n,f) and 64 l-rows vs all 256 centers,
// K=32. Thread 8 rows x 8 cols (acc 64). x rows l2-normalized during staging
// (8-lane shfl). Argmax of a*sim+b (sigmoid monotone) per row via 32-lane
// shfl_xor reduce with min-index tie rule; gather c_value, scale by
// sigmoid(max), write dispatched IN PLACE over xn (block owns its l x chan
// region exclusively).
// ---------------------------------------------------------------------------
__global__ __launch_bounds__(256) void sim_k(
    float* __restrict__ xn, const float* __restrict__ cpn,
    const float* __restrict__ cval, const float* __restrict__ alphap,
    const float* __restrict__ betap) {
  __shared__ float Xs[64 * 32];    //  8 KB
  __shared__ float Csh[256 * 32];  // 32 KB
  int t = threadIdx.x;
  int tc = t & 31, tr = t >> 5;  // 32 thread-cols x 8 thread-rows
  int lt = blockIdx.x & 63;      // l-tile of 64
  int nf = blockIdx.x >> 6;      // 0..31
  int f = nf & 7, nI = nf >> 3;
  int l0 = lt * 64;

  const float* cp = cpn + (size_t)nf * Ss * SC;
  // stage centers 256x32 (8 float4/thread)
#pragma unroll
  for (int it = 0; it < 8; it++) {
    int i2 = t + 256 * it;
    int c = i2 >> 3, j = i2 & 7;
    float4 v = *(const float4*)(cp + c * SC + 4 * j);
    *(float4*)&Csh[c * 32 + ((4 * j) ^ ((((c >> 3) ^ c) & 7) << 2))] = v;
  }
  // stage x rows 64x32, normalized on the fly (8 lanes per row)
#pragma unroll
  for (int it = 0; it < 2; it++) {
    int i2 = t + 256 * it;
    int r = i2 >> 3, j = i2 & 7;
    float4 v = *(const float4*)(xn + ((size_t)nI * Ll + l0 + r) * Cc + f * SC + 4 * j);
    float ss = v.x * v.x + v.y * v.y + v.z * v.z + v.w * v.w;
    ss += __shfl_xor(ss, 1, 64);
    ss += __shfl_xor(ss, 2, 64);
    ss += __shfl_xor(ss, 4, 64);
    float rin = 1.f / fmaxf(sqrtf(ss), 1e-12f);
    v.x *= rin; v.y *= rin; v.z *= rin; v.w *= rin;
    *(float4*)&Xs[r * 32 + ((4 * j) ^ ((((r >> 3) ^ r) & 7) << 2))] = v;
  }
  __syncthreads();

  float acc[8][8];
#pragma unroll
  for (int i = 0; i < 8; i++)
#pragma unroll
    for (int c = 0; c < 8; c++) acc[i][c] = 0.f;

#pragma unroll
  for (int kq = 0; kq < 8; kq++) {
    float4 Av[8];
#pragma unroll
    for (int i = 0; i < 8; i++)
      Av[i] = *(const float4*)&Xs[(8 * tr + i) * 32 +
                                  ((4 * kq) ^ (((tr ^ i) & 7) << 2))];
#pragma unroll
    for (int c = 0; c < 8; c++) {
      float4 Bv = *(const float4*)&Csh[(8 * tc + c) * 32 +
                                       ((4 * kq) ^ (((tc ^ c) & 7) << 2))];
#pragma unroll
      for (int i = 0; i < 8; i++) {
        acc[i][c] = fmaf(Av[i].x, Bv.x, acc[i][c]);
        acc[i][c] = fmaf(Av[i].y, Bv.y, acc[i][c]);
        acc[i][c] = fmaf(Av[i].z, Bv.z, acc[i][c]);
        acc[i][c] = fmaf(Av[i].w, Bv.w, acc[i][c]);
      }
    }
  }

  float a = alphap[0], bt = betap[0];
#pragma unroll
  for (int i = 0; i < 8; i++) {
    float best = -3.0e38f;
    int bi = 0;
#pragma unroll
    for (int c = 0; c < 8; c++) {
      float tv = fmaf(a, acc[i][c], bt);
      if (tv > best) { best = tv; bi = 8 * tc + c; }  // first-max within thread
    }
#pragma unroll
    for (int m = 1; m <= 16; m <<= 1) {
      float ov = __shfl_xor(best, m, 64);
      int oi = __shfl_xor(bi, m, 64);
      if (ov > best || (ov == best && oi < bi)) { best = ov; bi = oi; }
    }
    float mv = 1.f / (1.f + expf(-best));
    float val = cval[((size_t)nf * Ss + bi) * SC + tc] * mv;
    xn[((size_t)nI * Ll + l0 + 8 * tr + i) * Cc + f * SC + tc] = val;
  }
}

// ---------------------------------------------------------------------------
extern "C" void kernel_launch(void* const* d_in, const int* in_sizes, int n_in,
                              void* d_out, int out_size, void* d_ws, size_t ws_size,
                              hipStream_t stream) {
  const float* x0      = (const float*)d_in[0];
  const float* center1 = (const float*)d_in[1];
  const float* W0      = (const float*)d_in[2];
  const float* b0      = (const float*)d_in[3];
  const float* W1      = (const float*)d_in[4];
  const float* b1      = (const float*)d_in[5];
  const float* Wm      = (const float*)d_in[6];
  const float* bm      = (const float*)d_in[7];
  const float* alpha   = (const float*)d_in[8];
  const float* beta    = (const float*)d_in[9];
  float* out = (float*)d_out;
  float* ws  = (float*)d_ws;

  float* xn   = ws;                              // 16 MB: x0p, then dispatched in-place
  float* cpn  = xn + (size_t)Nn * Ll * Cc;       // 1 MB
  float* cval = cpn + (size_t)Nn * FC * Ss * SC; // 1 MB
  float* c1t  = xn;  // 2 MB overlay: consumed by split_k BEFORE x0p writes xn
  // total ws use: 18 MB

  // c1 = center1 @ W1^T + b1  (M=1024, N=512)
  gemm_k<<<dim3(Nn * Ss / 128, 512 / 64), dim3(128), 0, stream>>>(
      center1, W1, b1, c1t, 512);
  // split + l2norm centers
  split_k<<<dim3(1024), dim3(256), 0, stream>>>(c1t, cpn, cval);
  // x0p = x0 @ W0^T + b0  (M=16384, N=256); overwrites the c1t overlay
  gemm_k<<<dim3(Nn * Ll / 128, Cc / 64), dim3(128), 0, stream>>>(
      x0, W0, b0, xn, Cc);
  // sim + argmax + gather + scale, in place over xn
  sim_k<<<dim3(32 * 64), dim3(256), 0, stream>>>(xn, cpn, cval, alpha, beta);
  // out = dispatched @ Wm^T + bm
  gemm_k<<<dim3(Nn * Ll / 128, Cc / 64), dim3(128), 0, stream>>>(
      xn, Wm, bm, out, Cc);
}